// Round 6
// baseline (39.191 us; speedup 1.0000x reference)
//
#include <hip/hip_runtime.h>
#include <math.h>

// YOLO box decode: x[B=32, A*(NC+5)=255, G=52, G=52] f32 ->
// out[B, A*G*G=8112, 85] f32  (+ trailing scalar 0 from the tuple return).
//
// R1: TILE 64 (7 blocks/CU), float4 reads, native exp.      47.2 -> 37.6 us
// R3/R4: unrolled 6-deep load/store phases (MLP), NT stores. 37.6 -> 35.7 us
// R5: TILE=52 FAILED (38.7us): 208B segments straddle 128B lines shared
//     across XCDs -> FETCH 54->66MB. Lesson: tile byte extent % 128B == 0.
// R6: barrier-free wave-private tiles. Each wave owns 16 cells (5440B LDS),
//     block=128 = 2 waves covering 32 cells (128B/channel, line-aligned,
//     zero cross-XCD sharing). No __syncthreads -- wave-internal
//     s_waitcnt lgkmcnt(0) orders ds_write->ds_read. ~15 blocks/CU x 2
//     waves = ~30/32 waves, waves drain independently.

#define NB    32
#define NA    3
#define NCH   85
#define GG    52
#define CELLS (GG * GG)          // 2704 = 169 * 16
#define WCELL 16                 // cells per wave
#define BCELL 32                 // cells per block (2 waves)
#define NBLK  ((CELLS + BCELL - 1) / BCELL)   // 85 (last block: 1 wave idle)
#define STRIDEF 8.0f

typedef float f32x4 __attribute__((ext_vector_type(4)));

__device__ __forceinline__ float sigm(float v) {
    return __fdividef(1.0f, 1.0f + __expf(-v));
}

__global__ __launch_bounds__(128, 8) void yolo_decode(const float* __restrict__ x,
                                                      float* __restrict__ out,
                                                      long long out_size) {
    __shared__ __align__(16) float lds[2][WCELL * NCH];   // 2 x 5440B

    const int a = blockIdx.y;
    const int b = blockIdx.z;

    const int lane = threadIdx.x & 63;
    const int wv   = threadIdx.x >> 6;                // 0..1
    const int cell0 = blockIdx.x * BCELL + wv * WCELL;

    const float aw = (a == 0) ? 10.0f : (a == 1) ? 16.0f : 33.0f;
    const float ah = (a == 0) ? 13.0f : (a == 1) ? 30.0f : 23.0f;

    // fold the tuple's trailing scalar 0 into this kernel (no extra launch)
    const long long MAIN = (long long)NB * NA * CELLS * NCH;
    if (blockIdx.x == 0 && a == 0 && b == 0 && threadIdx.x == 0 && out_size > MAIN) {
        for (long long i = MAIN; i < out_size; ++i) out[i] = 0.0f;
    }

    if (cell0 >= CELLS) return;                       // last block, wave 1

    // this wave's input base at cell0
    const float* xb = x + ((size_t)(b * NA + a) * NCH) * CELLS + cell0;
    float* ldsW = lds[wv];

    const int start = lane >> 2;                      // channel group 0..15
    const int c4    = (lane & 3) * 4;                 // local cell (x4), 0..12

    float gx[4], gy[4];
    #pragma unroll
    for (int j = 0; j < 4; ++j) {
        const int cell = cell0 + c4 + j;
        gx[j] = (float)(cell % GG);
        gy[j] = (float)(cell / GG);
    }

    // channels: start + 16k. k=0..4 always (ch<=79); k=5 iff start<5.
    // Issue ALL loads first -> 5-6 outstanding global loads per thread.
    f32x4 v[6];
    #pragma unroll
    for (int k = 0; k < 5; ++k)
        v[k] = *(const f32x4*)(xb + (size_t)(start + 16 * k) * CELLS + c4);
    const bool has6 = (start < 5);
    if (has6)
        v[5] = *(const f32x4*)(xb + (size_t)(start + 80) * CELLS + c4);

    // transform; only k==0 can hit the 4 special channels (ch=start<16)
    {
        float r[4] = {v[0].x, v[0].y, v[0].z, v[0].w};
        if (start == 0) {
            #pragma unroll
            for (int j = 0; j < 4; ++j) r[j] = (sigm(r[j]) + gx[j]) * STRIDEF;
        } else if (start == 1) {
            #pragma unroll
            for (int j = 0; j < 4; ++j) r[j] = (sigm(r[j]) + gy[j]) * STRIDEF;
        } else if (start == 2) {
            #pragma unroll
            for (int j = 0; j < 4; ++j) r[j] = __expf(r[j]) * aw;
        } else if (start == 3) {
            #pragma unroll
            for (int j = 0; j < 4; ++j) r[j] = __expf(r[j]) * ah;
        } else {
            #pragma unroll
            for (int j = 0; j < 4; ++j) r[j] = sigm(r[j]);
        }
        #pragma unroll
        for (int j = 0; j < 4; ++j) ldsW[(c4 + j) * NCH + start] = r[j];
    }
    #pragma unroll
    for (int k = 1; k < 5; ++k) {
        const int ch = start + 16 * k;
        float r[4] = {v[k].x, v[k].y, v[k].z, v[k].w};
        #pragma unroll
        for (int j = 0; j < 4; ++j) ldsW[(c4 + j) * NCH + ch] = sigm(r[j]);
    }
    if (has6) {
        const int ch = start + 80;
        float r[4] = {v[5].x, v[5].y, v[5].z, v[5].w};
        #pragma unroll
        for (int j = 0; j < 4; ++j) ldsW[(c4 + j) * NCH + ch] = sigm(r[j]);
    }

    // wave-internal fence: all 64 lanes' ds_writes complete before ds_reads.
    // (no __syncthreads -- the other wave never touches our LDS region)
    asm volatile("s_waitcnt lgkmcnt(0)" ::: "memory");
    __builtin_amdgcn_sched_barrier(0);

    // coalesced writeback: 16*85 = 1360 floats = 340 float4, contiguous,
    // base 5440B-aligned (64B ok). k=0..4 full rounds + 20 lanes on k=5.
    float* ob = out + ((size_t)((b * NA + a) * CELLS + cell0)) * NCH;
    const f32x4* l4 = (const f32x4*)ldsW;
    f32x4* o4 = (f32x4*)ob;

    f32x4 t[6];
    #pragma unroll
    for (int k = 0; k < 5; ++k) t[k] = l4[lane + 64 * k];
    const bool has6w = (lane < 340 - 320);
    if (has6w) t[5] = l4[lane + 320];

    #pragma unroll
    for (int k = 0; k < 5; ++k)
        __builtin_nontemporal_store(t[k], &o4[lane + 64 * k]);
    if (has6w)
        __builtin_nontemporal_store(t[5], &o4[lane + 320]);
}

extern "C" void kernel_launch(void* const* d_in, const int* in_sizes, int n_in,
                              void* d_out, int out_size, void* d_ws, size_t ws_size,
                              hipStream_t stream) {
    const float* x = (const float*)d_in[0];
    float* out = (float*)d_out;

    dim3 grid(NBLK, NA, NB);        // 85 x 3 x 32 = 8160 blocks of 128
    yolo_decode<<<grid, 128, 0, stream>>>(x, out, (long long)out_size);
}